// Round 5
// baseline (124.642 us; speedup 1.0000x reference)
//
#include <hip/hip_runtime.h>

#define CONS_RATE 0.001f
#define CLAMP_V   10.0f

// e^(2s) = 2^(s * 2/ln2)
#define TWO_LOG2E 2.88539008177792681472f

#if defined(__has_builtin)
#  if __has_builtin(__builtin_amdgcn_exp2f)
#    define EXP2F(x) __builtin_amdgcn_exp2f(x)
#  endif
#endif
#ifndef EXP2F
#  define EXP2F(x) __expf(0.69314718055994530942f * (x))
#endif

typedef float f32x4 __attribute__((ext_vector_type(4)));

__device__ __forceinline__ float rf(float x) {
    // force wave-uniform value into an SGPR
    return __uint_as_float(__builtin_amdgcn_readfirstlane(__float_as_uint(x)));
}

// Per-element: out = clamp(w + 0.001*tanh(s)),
//   s = b2 + sum_j v_j * relu(a_j*w + c_j)
// Rewrite: v*relu(x) = 0.5*v*x + 0.5*v*|x|, |a*w+c| = |a|*|w - t|, t = -c/a
//   => s = P + Q*w + sum_j u_j * |w - t_j|
//   P = b2 + 0.5*sum v_j c_j,  Q = 0.5*sum v_j a_j,  u_j = 0.5*v_j*|a_j|
// Each term: v_sub_f32 (SGPR t in src0) + v_fma with FREE abs() modifier
// = 2 VALU ops/term instead of 3. All coefficients live in SGPRs.

__global__ __launch_bounds__(256) void ConsolidationDynamics_70068096467285_kernel(
    const float* __restrict__ w,
    const float* __restrict__ cs_p,
    const float* __restrict__ fs_p,
    const float* __restrict__ W1,   // (3,16) row-major
    const float* __restrict__ b1,   // (16,)
    const float* __restrict__ W2,   // (16,1)
    const float* __restrict__ b2,   // (1,)
    float* __restrict__ out,
    int n)
{
    const float cs = cs_p[0];
    const float fs = fs_p[0];

    float P = b2[0];
    float Q = 0.0f;

    // Precompute t_j (breakpoints) and u_j (slopes); guard a==0 exactly.
    // One-time cost (~16 precise divides) hides under the first load latency.
#define COEF(J) \
    float t##J, u##J; { \
        const float a = W1[J]; \
        const float v = W2[J]; \
        const float c = fmaf(cs, W1[16 + J], fmaf(fs, W1[32 + J], b1[J])); \
        P = fmaf(0.5f * v, c, P); \
        Q = fmaf(0.5f * v, a, Q); \
        if (a != 0.0f) { t##J = rf(-c / a); u##J = rf(0.5f * v * fabsf(a)); } \
        else { t##J = 0.0f; u##J = 0.0f; P = fmaf(v, fmaxf(c, 0.0f) - 0.5f * c, P); } \
    }
    COEF(0)  COEF(1)  COEF(2)  COEF(3)
    COEF(4)  COEF(5)  COEF(6)  COEF(7)
    COEF(8)  COEF(9)  COEF(10) COEF(11)
    COEF(12) COEF(13) COEF(14) COEF(15)
#undef COEF
    P = rf(P);
    Q = rf(Q);

#define TERM(J, sacc) sacc = fmaf(u##J, fabsf(t##J - r_), sacc);

#define EVAL(rr, d) { \
    const float r_ = (rr); \
    float s0 = fmaf(r_, Q, P); \
    float s1 = u1 * fabsf(t1 - r_); \
    TERM(0, s0)  TERM(2, s0)  TERM(3, s1)  TERM(4, s0)  TERM(5, s1) \
    TERM(6, s0)  TERM(7, s1)  TERM(8, s0)  TERM(9, s1)  TERM(10, s0) \
    TERM(11, s1) TERM(12, s0) TERM(13, s1) TERM(14, s0) TERM(15, s1) \
    const float e  = EXP2F((s0 + s1) * TWO_LOG2E); \
    const float u  = fmaf(-2.0f, __builtin_amdgcn_rcpf(e + 1.0f), 1.0f); \
    const float nw = fmaf(u, CONS_RATE, r_); \
    (d) = fminf(fmaxf(nw, -CLAMP_V), CLAMP_V); }

#define EVAL4(V, O) \
    EVAL((V).x, (O).x) EVAL((V).y, (O).y) EVAL((V).z, (O).z) EVAL((V).w, (O).w)

    const int n4 = n >> 2;
    const f32x4* __restrict__ w4 = (const f32x4*)w;
    f32x4* __restrict__ o4 = (f32x4*)out;

    const int tid  = threadIdx.x;
    // One-shot: each thread owns 4 coalesced float4 (16 elements); no loop.
    // Block churn (16 blocks/CU over the dispatch) staggers load/store phases
    // across the device instead of the grid-stride convoy.
    const int base = blockIdx.x * 1024 + tid;
    const int i0 = base, i1 = base + 256, i2 = base + 512, i3 = base + 768;

    if (i3 < n4) {
        const f32x4 A = w4[i0];
        const f32x4 B = w4[i1];
        const f32x4 C = w4[i2];
        const f32x4 D = w4[i3];
        f32x4 oA, oB, oC, oD;
        EVAL4(A, oA) EVAL4(B, oB) EVAL4(C, oC) EVAL4(D, oD)
        __builtin_nontemporal_store(oA, &o4[i0]);
        __builtin_nontemporal_store(oB, &o4[i1]);
        __builtin_nontemporal_store(oC, &o4[i2]);
        __builtin_nontemporal_store(oD, &o4[i3]);
    } else {
        // Partial last block: guarded per-float4.
        for (int k = 0; k < 4; ++k) {
            const int idx = base + (k << 8);
            if (idx < n4) {
                const f32x4 A = w4[idx];
                f32x4 oA;
                EVAL4(A, oA)
                __builtin_nontemporal_store(oA, &o4[idx]);
            }
        }
    }
    // Scalar tail (n % 4), handled by block 0.
    if (blockIdx.x == 0) {
        const int rem = n & 3;
        if (tid < rem) {
            const float r = w[(n4 << 2) + tid];
            float d;
            EVAL(r, d)
            out[(n4 << 2) + tid] = d;
        }
    }
#undef EVAL4
#undef EVAL
#undef TERM
}

extern "C" void kernel_launch(void* const* d_in, const int* in_sizes, int n_in,
                              void* d_out, int out_size, void* d_ws, size_t ws_size,
                              hipStream_t stream) {
    const float* w   = (const float*)d_in[0];
    const float* cs  = (const float*)d_in[1];
    const float* fs  = (const float*)d_in[2];
    const float* W1  = (const float*)d_in[3];
    const float* b1  = (const float*)d_in[4];
    const float* W2  = (const float*)d_in[5];
    const float* b2  = (const float*)d_in[6];
    float* out = (float*)d_out;

    const int n  = in_sizes[0];
    const int n4 = n >> 2;
    // One float4-quad (1024 float4s = 4096 elements) per 256-thread block.
    const int block = 256;
    int grid = (n4 + 1023) >> 10;
    if (grid < 1) grid = 1;

    ConsolidationDynamics_70068096467285_kernel<<<grid, block, 0, stream>>>(
        w, cs, fs, W1, b1, W2, b2, out, n);
}

// Round 6
// 123.955 us; speedup vs baseline: 1.0055x; 1.0055x over previous
//
#include <hip/hip_runtime.h>

#define CONS_RATE 0.001f
#define CLAMP_V   10.0f

// e^(2s) = 2^(s * 2/ln2)
#define TWO_LOG2E 2.88539008177792681472f

#if defined(__has_builtin)
#  if __has_builtin(__builtin_amdgcn_exp2f)
#    define EXP2F(x) __builtin_amdgcn_exp2f(x)
#  endif
#endif
#ifndef EXP2F
#  define EXP2F(x) __expf(0.69314718055994530942f * (x))
#endif

typedef float f32x4 __attribute__((ext_vector_type(4)));

__device__ __forceinline__ float rf(float x) {
    // force wave-uniform value into an SGPR
    return __uint_as_float(__builtin_amdgcn_readfirstlane(__float_as_uint(x)));
}

// Per-element: out = clamp(w + 0.001*tanh(s)),
//   s = b2 + sum_j v_j * relu(a_j*w + c_j)
// Rewrite: v*relu(x) = 0.5*v*x + 0.5*v*|x|, |a*w+c| = |a|*|w - t|, t = -c/a
//   => s = P + Q*w + sum_j u_j * |w - t_j|
// Each term: v_sub (SGPR t) + v_fma with free abs() modifier = 2 VALU ops.
//
// Round-6 change: contiguous-slab partitioning. All previous variants
// interleaved the 64MB array across thousands of blocks -> the memory
// controller served ~8K scattered 1KB streams (row-buffer thrash, ~3.4 TB/s).
// The harness's own fillBuffer hits 6.3 TB/s with FEW waves sweeping LONG
// contiguous ranges. Here: 1024 blocks (4/CU), each owns a contiguous
// 16K-element slab, walked sequentially with a depth-4 register pipeline.

__global__ __launch_bounds__(256) void ConsolidationDynamics_70068096467285_kernel(
    const float* __restrict__ w,
    const float* __restrict__ cs_p,
    const float* __restrict__ fs_p,
    const float* __restrict__ W1,   // (3,16) row-major
    const float* __restrict__ b1,   // (16,)
    const float* __restrict__ W2,   // (16,1)
    const float* __restrict__ b2,   // (1,)
    float* __restrict__ out,
    int n)
{
    const float cs = cs_p[0];
    const float fs = fs_p[0];

    float P = b2[0];
    float Q = 0.0f;

#define COEF(J) \
    float t##J, u##J; { \
        const float a = W1[J]; \
        const float v = W2[J]; \
        const float c = fmaf(cs, W1[16 + J], fmaf(fs, W1[32 + J], b1[J])); \
        P = fmaf(0.5f * v, c, P); \
        Q = fmaf(0.5f * v, a, Q); \
        if (a != 0.0f) { t##J = rf(-c / a); u##J = rf(0.5f * v * fabsf(a)); } \
        else { t##J = 0.0f; u##J = 0.0f; P = fmaf(v, fmaxf(c, 0.0f) - 0.5f * c, P); } \
    }
    COEF(0)  COEF(1)  COEF(2)  COEF(3)
    COEF(4)  COEF(5)  COEF(6)  COEF(7)
    COEF(8)  COEF(9)  COEF(10) COEF(11)
    COEF(12) COEF(13) COEF(14) COEF(15)
#undef COEF
    P = rf(P);
    Q = rf(Q);

#define TERM(J, sacc) sacc = fmaf(u##J, fabsf(t##J - r_), sacc);

#define EVAL(rr, d) { \
    const float r_ = (rr); \
    float s0 = fmaf(r_, Q, P); \
    float s1 = u1 * fabsf(t1 - r_); \
    TERM(0, s0)  TERM(2, s0)  TERM(3, s1)  TERM(4, s0)  TERM(5, s1) \
    TERM(6, s0)  TERM(7, s1)  TERM(8, s0)  TERM(9, s1)  TERM(10, s0) \
    TERM(11, s1) TERM(12, s0) TERM(13, s1) TERM(14, s0) TERM(15, s1) \
    const float e  = EXP2F((s0 + s1) * TWO_LOG2E); \
    const float u  = fmaf(-2.0f, __builtin_amdgcn_rcpf(e + 1.0f), 1.0f); \
    const float nw = fmaf(u, CONS_RATE, r_); \
    (d) = fminf(fmaxf(nw, -CLAMP_V), CLAMP_V); }

#define EVAL4(V, O) \
    EVAL((V).x, (O).x) EVAL((V).y, (O).y) EVAL((V).z, (O).z) EVAL((V).w, (O).w)

    const int n4 = n >> 2;                     // float4 count
    const f32x4* __restrict__ w4 = (const f32x4*)w;
    f32x4* __restrict__ o4 = (f32x4*)out;

    const int tid  = threadIdx.x;
    // Each block owns a CONTIGUOUS slab of 4096 float4 (16384 elements).
    const int slab = blockIdx.x << 12;
    const f32x4* __restrict__ src = w4 + slab + tid;
    f32x4* __restrict__ dst = o4 + slab + tid;

    if (slab + 4096 <= n4) {
        // Fast path: full slab, 16 float4/thread, depth-4 register pipeline.
        // Loads for step k+4..k+7 are issued BEFORE computing k..k+3, so
        // ~2KB/wave stays outstanding while the CU sweeps the slab
        // sequentially (4KB address steps -> DRAM row-buffer friendly).
        f32x4 A = src[0 * 256];
        f32x4 B = src[1 * 256];
        f32x4 C = src[2 * 256];
        f32x4 D = src[3 * 256];
#pragma unroll 1
        for (int k = 0; k < 12; k += 4) {
            const f32x4 nA = src[(k + 4) * 256];
            const f32x4 nB = src[(k + 5) * 256];
            const f32x4 nC = src[(k + 6) * 256];
            const f32x4 nD = src[(k + 7) * 256];
            f32x4 oA, oB, oC, oD;
            EVAL4(A, oA) EVAL4(B, oB) EVAL4(C, oC) EVAL4(D, oD)
            __builtin_nontemporal_store(oA, &dst[(k + 0) * 256]);
            __builtin_nontemporal_store(oB, &dst[(k + 1) * 256]);
            __builtin_nontemporal_store(oC, &dst[(k + 2) * 256]);
            __builtin_nontemporal_store(oD, &dst[(k + 3) * 256]);
            A = nA; B = nB; C = nC; D = nD;
        }
        // Drain: last 4 float4s.
        f32x4 oA, oB, oC, oD;
        EVAL4(A, oA) EVAL4(B, oB) EVAL4(C, oC) EVAL4(D, oD)
        __builtin_nontemporal_store(oA, &dst[12 * 256]);
        __builtin_nontemporal_store(oB, &dst[13 * 256]);
        __builtin_nontemporal_store(oC, &dst[14 * 256]);
        __builtin_nontemporal_store(oD, &dst[15 * 256]);
    } else {
        // Partial last slab: guarded per-float4.
        for (int k = 0; k < 16; ++k) {
            const int idx = slab + (k << 8) + tid;
            if (idx < n4) {
                const f32x4 A = w4[idx];
                f32x4 oA;
                EVAL4(A, oA)
                __builtin_nontemporal_store(oA, &o4[idx]);
            }
        }
    }
    // Scalar tail (n % 4), handled by block 0.
    if (blockIdx.x == 0) {
        const int rem = n & 3;
        if (tid < rem) {
            const float r = w[(n4 << 2) + tid];
            float d;
            EVAL(r, d)
            out[(n4 << 2) + tid] = d;
        }
    }
#undef EVAL4
#undef EVAL
#undef TERM
}

extern "C" void kernel_launch(void* const* d_in, const int* in_sizes, int n_in,
                              void* d_out, int out_size, void* d_ws, size_t ws_size,
                              hipStream_t stream) {
    const float* w   = (const float*)d_in[0];
    const float* cs  = (const float*)d_in[1];
    const float* fs  = (const float*)d_in[2];
    const float* W1  = (const float*)d_in[3];
    const float* b1  = (const float*)d_in[4];
    const float* W2  = (const float*)d_in[5];
    const float* b2  = (const float*)d_in[6];
    float* out = (float*)d_out;

    const int n  = in_sizes[0];
    const int n4 = n >> 2;
    // 1024 blocks for n=4096^2: 4 blocks/CU, 128/XCD, each sweeping a
    // contiguous 64KB-in + 64KB-out slab.
    const int block = 256;
    int grid = (n4 + 4095) >> 12;
    if (grid < 1) grid = 1;

    ConsolidationDynamics_70068096467285_kernel<<<grid, block, 0, stream>>>(
        w, cs, fs, W1, b1, W2, b2, out, n);
}